// Round 1
// baseline (227.250 us; speedup 1.0000x reference)
//
#include <hip/hip_runtime.h>

#define N_NODES 8192
#define N_EDGES 65536
#define FEAT    136
#define WNUM    3392

typedef __attribute__((ext_vector_type(4))) short s16x4;
typedef __attribute__((ext_vector_type(8))) short s16x8;
typedef __attribute__((ext_vector_type(4))) float f32x4;
typedef __attribute__((ext_vector_type(2))) float f32x2;

__device__ __forceinline__ float b2f(unsigned short h) {
    union { unsigned int u; float f; } v; v.u = ((unsigned int)h) << 16; return v.f;
}
__device__ __forceinline__ unsigned short f2b(float f) {
    union { float f; unsigned int u; } v; v.f = f;
    unsigned int u = v.u;
    unsigned int r = (u + 0x7FFFu + ((u >> 16) & 1u)) >> 16;
    return (unsigned short)r;
}

// total scale for W2 column `col` = 1/sqrt(fan_in) * per-i sub-factor (inv_s3/inv_s2)
__device__ __forceinline__ float wscale(int col) {
    const float inv_s3 = 0.57735026918962576f;
    const float inv_s2 = 0.70710678118654752f;
    if (col < 1536) { int i = col >> 5;          return 0.14433756729740643f * (i < 32 ? 1.f : inv_s3); }
    if (col < 2560) { int i = (col - 1536) >> 4; return 0.125f               * (i >= 48 ? inv_s2 : 1.f); }
    if (col < 3200) { int i = (col - 2560) >> 4; return 0.15811388300841897f * (i < 16 ? inv_s2 : 1.f); }
    {               int i = (col - 3200) >> 3;   return 0.20412414523193150f * (i < 16 ? inv_s3 : 1.f); }
}

// ---- prep: W2 -> w2t in MFMA-FRAGMENT order (bf16, scale folded); W1 -> w1t; b2 -> b2s ----
// w2t layout (shorts): [chunk c (64 cols)][t 0..3][half 0..1][lane 0..63][j 0..7]
//   element = W2scaled[k = half*32 + (lane>>4)*8 + j][col = c*64 + t*16 + (lane&15)]
// so the main kernel's per-(c,t) A-fragment load is one fully-contiguous 1KB wave load.
__global__ void transpose_kernel(const float* __restrict__ w2,
                                 const float* __restrict__ w1,
                                 const float* __restrict__ bias2,
                                 unsigned short* __restrict__ w2t,
                                 unsigned short* __restrict__ w1t,
                                 float* __restrict__ b2s) {
    __shared__ float tl[64 * 65];
    const int b = blockIdx.x, tid = threadIdx.x;
    if (b < 53) {
        const int c0 = b * 64;
        for (int idx = tid; idx < 4096; idx += 256) {
            int k = idx >> 6, c = idx & 63;
            tl[c * 65 + k] = w2[k * WNUM + c0 + c];          // coalesced read over c
        }
        __syncthreads();
        for (int idx = tid; idx < 4096; idx += 256) {
            int fl   = idx >> 10;            // t
            int rem  = idx & 1023;
            int half = rem >> 9;
            int ln   = (rem >> 3) & 63;
            int j    = idx & 7;
            int q = ln >> 4, nn = ln & 15;
            int cl  = fl * 16 + nn;
            int k   = half * 32 + q * 8 + j;
            int col = c0 + cl;
            w2t[(size_t)b * 4096 + idx] = f2b(tl[cl * 65 + k] * wscale(col));
        }
        if (tid < 64) {
            int col = c0 + tid;
            b2s[col] = bias2[col] * wscale(col);
        }
    } else {
        for (int idx = tid; idx < 4096; idx += 256) {
            int k = idx >> 6, j = idx & 63;
            tl[j * 65 + k] = w1[k * 64 + j];
        }
        __syncthreads();
        for (int idx = tid; idx < 4096; idx += 256) {
            int j = idx >> 6, k = idx & 63;
            w1t[j * 64 + k] = f2b(tl[j * 65 + k]);
        }
    }
}

// ---------------- fused main kernel: 64 edges per block, NO in-loop barriers ----------------
__global__ __launch_bounds__(256, 4)
void tpconv_main(const float* __restrict__ node_attr,
                 const int* __restrict__ edge_index,
                 const float* __restrict__ edge_attr,
                 const float* __restrict__ edge_sh,
                 const unsigned short* __restrict__ w1t,
                 const float* __restrict__ b1,
                 const unsigned short* __restrict__ w2t,
                 const float* __restrict__ b2s,
                 float* __restrict__ acc_g,
                 float* __restrict__ cnt_g) {
    // LDS layout (37632 B total -> 4 blocks/CU):
    //  [0, 18944)      x gather, bf16, 64 rows x stride 148
    //  [18944, 28160)  h tile, bf16, 64 x 72
    //  [28160, 29184)  sh, f32, 64 x 4
    //  [37120, 37632)  src, dst (int 64 each)  -- kept outside stage region
    //  after K-loop: [0, 37120) reused as f32 Y staging, 64 rows x stride 145
    __shared__ __align__(16) char smem[37632];
    unsigned short* x_lds = (unsigned short*)smem;
    unsigned short* h_lds = (unsigned short*)(smem + 18944);
    float* sh_lds = (float*)(smem + 28160);
    int* src_lds  = (int*)(smem + 37120);
    int* dst_lds  = (int*)(smem + 37376);

    const int tid  = threadIdx.x;
    const int lane = tid & 63;
    const int wv   = tid >> 6;       // wave 0..3 -> 16-edge stripe
    const int n    = lane & 15;
    const int quad = lane >> 4;
    const int eb   = blockIdx.x * 64;

    // ---- indices, sh, counts ----
    if (tid < 64) {
        int s = edge_index[eb + tid];
        int d = edge_index[N_EDGES + eb + tid];
        src_lds[tid] = s;
        dst_lds[tid] = d;
        atomicAdd(&cnt_g[s], 1.0f);
        const float4 shv = *(const float4*)&edge_sh[(size_t)(eb + tid) * 4];
        sh_lds[tid * 4 + 0] = shv.x;
        sh_lds[tid * 4 + 1] = shv.y;
        sh_lds[tid * 4 + 2] = shv.z;
        sh_lds[tid * 4 + 3] = shv.w;
    }

    // ---- h = relu(ea @ W1 + b1) via MFMA -> h_lds ----
    {
        const float* ea = edge_attr + (size_t)(eb + wv * 16 + n) * 64 + quad * 8;
        s16x8 a0, a1;
#pragma unroll
        for (int j = 0; j < 8; ++j) {
            a0[j] = (short)f2b(ea[j]);        // A[m=n][k=quad*8+j]
            a1[j] = (short)f2b(ea[32 + j]);
        }
        for (int ct = 0; ct < 4; ++ct) {
            int col = ct * 16 + n;
            const unsigned short* wp = w1t + col * 64;
            s16x8 bu0 = *(const s16x8*)&wp[quad * 8];
            s16x8 bu1 = *(const s16x8*)&wp[32 + quad * 8];
            f32x4 acc = {0.f, 0.f, 0.f, 0.f};
            acc = __builtin_amdgcn_mfma_f32_16x16x32_bf16(a0, bu0, acc, 0, 0, 0);
            acc = __builtin_amdgcn_mfma_f32_16x16x32_bf16(a1, bu1, acc, 0, 0, 0);
            float bias = b1[col];
            for (int r = 0; r < 4; ++r) {
                float hv = acc[r] + bias;
                hv = hv > 0.f ? hv : 0.f;
                h_lds[(wv * 16 + quad * 4 + r) * 72 + col] = f2b(hv);
            }
        }
    }
    __syncthreads();   // dst_lds + h visible

    // ---- x gather: node_attr[dst] (f32) -> bf16, stride 148 ----
    for (int idx = tid; idx < 64 * 34; idx += 256) {
        int e = idx / 34, seg = idx - e * 34;
        const float4 v = *(const float4*)(node_attr + (size_t)dst_lds[e] * FEAT + seg * 4);
        s16x4 pk;
        pk[0] = (short)f2b(v.x); pk[1] = (short)f2b(v.y);
        pk[2] = (short)f2b(v.z); pk[3] = (short)f2b(v.w);
        *(s16x4*)&x_lds[e * 148 + seg * 4] = pk;
    }
    __syncthreads();   // x, sh visible

    // ---- per-lane state: lane owns edge eLoc ----
    const int eLoc = wv * 16 + n;
    const unsigned short* xr = &x_lds[eLoc * 148];
    const float sh0 = sh_lds[eLoc * 4 + 0];
    const float s1x = sh_lds[eLoc * 4 + 1];
    const float s1y = sh_lds[eLoc * 4 + 2];
    const float s1z = sh_lds[eLoc * 4 + 3];

    const unsigned short* hp = &h_lds[eLoc * 72];
    s16x8 h0 = *(const s16x8*)&hp[quad * 8];          // B[k=quad*8+j][n=edge]
    s16x8 h1 = *(const s16x8*)&hp[32 + quad * 8];

    f32x2 Y0e2[2][2] = {};   // [row-pair][kk]: element s = acc row 2p+s
    f32x2 Y1o2[2][3] = {};   // [row-pair][comp]
    f32x2 Y1e2[2][3] = {};
    f32x2 Y0o2[2]    = {};

    // Per-chunk A-fragment + bias loads, straight from global (L1/L2-resident w2t).
#define CHUNK_LOADS(c)                                                        \
    s16x8 a0f[4], a1f[4]; f32x4 bvv[4];                                       \
    {                                                                         \
        const unsigned short* gp = w2t + ((size_t)(c) << 12) + (lane << 3);   \
        _Pragma("unroll")                                                     \
        for (int t = 0; t < 4; ++t) {                                         \
            a0f[t] = *(const s16x8*)(gp + t * 1024);                          \
            a1f[t] = *(const s16x8*)(gp + t * 1024 + 512);                    \
        }                                                                     \
        _Pragma("unroll")                                                     \
        for (int t = 0; t < 4; ++t)                                           \
            bvv[t] = *(const f32x4*)(b2s + (c) * 64 + 16 * t + quad * 4);     \
    }

#define MFMA_T(t)                                                             \
    f32x4 acc = bvv[t];                                                       \
    acc = __builtin_amdgcn_mfma_f32_16x16x32_bf16(a0f[t], h0, acc, 0, 0, 0);  \
    acc = __builtin_amdgcn_mfma_f32_16x16x32_bf16(a1f[t], h1, acc, 0, 0, 0);  \
    f32x2 a01 = {acc[0], acc[1]}; f32x2 a23 = {acc[2], acc[3]};

#define ACC3(Y)                                                               \
    Y[0][0] += a01 * o0; Y[1][0] += a23 * o0;                                 \
    Y[0][1] += a01 * o1; Y[1][1] += a23 * o1;                                 \
    Y[0][2] += a01 * o2; Y[1][2] += a23 * o2;

    // ---- 0e, i < 32: x0e[i]*sh0 ----
    for (int c = 0; c < 16; ++c) {
        CHUNK_LOADS(c)
        float ov = 0.f;
#pragma unroll
        for (int t = 0; t < 4; ++t) {
            MFMA_T(t)
            if ((t & 1) == 0) ov = b2f(xr[2 * c + (t >> 1)]) * sh0;
            const int kk = t & 1;
            Y0e2[0][kk] += a01 * ov;
            Y0e2[1][kk] += a23 * ov;
        }
    }
    // ---- 0e, 32 <= i < 48: dot(x1o[i-32], sh1) ----
    for (int c = 16; c < 24; ++c) {
        CHUNK_LOADS(c)
        float ov = 0.f;
#pragma unroll
        for (int t = 0; t < 4; ++t) {
            MFMA_T(t)
            if ((t & 1) == 0) {
                int ib = 32 + 3 * (2 * c + (t >> 1) - 32);
                ov = b2f(xr[ib]) * s1x + b2f(xr[ib + 1]) * s1y + b2f(xr[ib + 2]) * s1z;
            }
            const int kk = t & 1;
            Y0e2[0][kk] += a01 * ov;
            Y0e2[1][kk] += a23 * ov;
        }
    }
    // ---- 1o, i < 32: x0e[i]*sh1 ----
    for (int c = 24; c < 32; ++c) {
        CHUNK_LOADS(c)
#pragma unroll
        for (int t = 0; t < 4; ++t) {
            MFMA_T(t)
            float xv = b2f(xr[4 * (c - 24) + t]);
            float o0 = xv * s1x, o1 = xv * s1y, o2 = xv * s1z;
            ACC3(Y1o2)
        }
    }
    // ---- 1o, 32 <= i < 48: x1o[i-32]*sh0 ----
    for (int c = 32; c < 36; ++c) {
        CHUNK_LOADS(c)
#pragma unroll
        for (int t = 0; t < 4; ++t) {
            MFMA_T(t)
            int ib = 32 + 3 * (4 * (c - 24) + t - 32);
            float o0 = b2f(xr[ib]) * sh0, o1 = b2f(xr[ib + 1]) * sh0, o2 = b2f(xr[ib + 2]) * sh0;
            ACC3(Y1o2)
        }
    }
    // ---- 1o, i >= 48: cross(x1e[i-48], sh1) ----
    for (int c = 36; c < 40; ++c) {
        CHUNK_LOADS(c)
#pragma unroll
        for (int t = 0; t < 4; ++t) {
            MFMA_T(t)
            int ib = 80 + 3 * (4 * (c - 24) + t - 48);
            float av0 = b2f(xr[ib]), av1 = b2f(xr[ib + 1]), av2 = b2f(xr[ib + 2]);
            float o0 = av1 * s1z - av2 * s1y;
            float o1 = av2 * s1x - av0 * s1z;
            float o2 = av0 * s1y - av1 * s1x;
            ACC3(Y1o2)
        }
    }
    // ---- 1e, i < 16: cross(x1o[i], sh1) ----
    for (int c = 40; c < 44; ++c) {
        CHUNK_LOADS(c)
#pragma unroll
        for (int t = 0; t < 4; ++t) {
            MFMA_T(t)
            int ib = 32 + 3 * (4 * (c - 40) + t);
            float av0 = b2f(xr[ib]), av1 = b2f(xr[ib + 1]), av2 = b2f(xr[ib + 2]);
            float o0 = av1 * s1z - av2 * s1y;
            float o1 = av2 * s1x - av0 * s1z;
            float o2 = av0 * s1y - av1 * s1x;
            ACC3(Y1e2)
        }
    }
    // ---- 1e, 16 <= i < 32: x1e[i-16]*sh0 ----
    for (int c = 44; c < 48; ++c) {
        CHUNK_LOADS(c)
#pragma unroll
        for (int t = 0; t < 4; ++t) {
            MFMA_T(t)
            int ib = 80 + 3 * (4 * (c - 40) + t - 16);
            float o0 = b2f(xr[ib]) * sh0, o1 = b2f(xr[ib + 1]) * sh0, o2 = b2f(xr[ib + 2]) * sh0;
            ACC3(Y1e2)
        }
    }
    // ---- 1e, i >= 32: x0o[i-32]*sh1 ----
    for (int c = 48; c < 50; ++c) {
        CHUNK_LOADS(c)
#pragma unroll
        for (int t = 0; t < 4; ++t) {
            MFMA_T(t)
            float xv = b2f(xr[128 + (4 * (c - 40) + t - 32)]);
            float o0 = xv * s1x, o1 = xv * s1y, o2 = xv * s1z;
            ACC3(Y1e2)
        }
    }
    // ---- 0o, i < 16: dot(x1e[i], sh1) ----
    for (int c = 50; c < 52; ++c) {
        CHUNK_LOADS(c)
#pragma unroll
        for (int t = 0; t < 4; ++t) {
            MFMA_T(t)
            int ib = 80 + 3 * (8 * (c - 50) + 2 * t + (quad >> 1));
            float ov = b2f(xr[ib]) * s1x + b2f(xr[ib + 1]) * s1y + b2f(xr[ib + 2]) * s1z;
            Y0o2[0] += a01 * ov;
            Y0o2[1] += a23 * ov;
        }
    }
    // ---- 0o, i >= 16: x0o[i-16]*sh0 ----
    {
        CHUNK_LOADS(52)
#pragma unroll
        for (int t = 0; t < 4; ++t) {
            MFMA_T(t)
            float ov = b2f(xr[128 + 2 * t + (quad >> 1)]) * sh0;
            Y0o2[0] += a01 * ov;
            Y0o2[1] += a23 * ov;
        }
    }
#undef ACC3
#undef MFMA_T
#undef CHUNK_LOADS

    // ---- stage Y rows in LDS (reuse x+h region, stride 145 breaks bank conflicts), then coalesced atomics ----
    __syncthreads();                          // everyone done reading x / h
    float* stage = (float*)smem;              // 64 rows x 145 f32
    {
        float* srow = stage + eLoc * 145;
#pragma unroll
        for (int r = 0; r < 4; ++r) {
            const int p = r >> 1, s = r & 1;
            int qr = quad * 4 + r;
            srow[qr]              = Y0e2[p][0][s];
            srow[16 + qr]         = Y0e2[p][1][s];
            srow[32 + qr * 3 + 0] = Y1o2[p][0][s];
            srow[32 + qr * 3 + 1] = Y1o2[p][1][s];
            srow[32 + qr * 3 + 2] = Y1o2[p][2][s];
            srow[80 + qr * 3 + 0] = Y1e2[p][0][s];
            srow[80 + qr * 3 + 1] = Y1e2[p][1][s];
            srow[80 + qr * 3 + 2] = Y1e2[p][2][s];
            srow[128 + (quad & 1) * 4 + r + (quad >> 1) * 8] = Y0o2[p][s];
        }
    }
    __syncthreads();
    // wave wv scatters its own 16 edges, lanes cover consecutive features (coalesced)
    for (int j = 0; j < 16; ++j) {
        int e = wv * 16 + j;
        float* dp = acc_g + (size_t)src_lds[e] * FEAT;
        const float* sr = stage + e * 145;
        atomicAdd(dp + lane,      sr[lane]);
        atomicAdd(dp + 64 + lane, sr[64 + lane]);
        if (lane < 8)
            atomicAdd(dp + 128 + lane, sr[128 + lane] + sr[136 + lane]);
    }
}

// ---------------- finalize: mean + residual (fp32 out) ----------------
__global__ void finalize_kernel(const float* __restrict__ acc_g,
                                const float* __restrict__ cnt_g,
                                const float* __restrict__ node_attr,
                                float* __restrict__ out) {
    int idx = blockIdx.x * 256 + threadIdx.x;
    if (idx >= N_NODES * FEAT) return;
    int nn = idx / FEAT;
    float c = cnt_g[nn];
    out[idx] = acc_g[idx] / fmaxf(c, 1.0f) + node_attr[idx];
}

extern "C" void kernel_launch(void* const* d_in, const int* in_sizes, int n_in,
                              void* d_out, int out_size, void* d_ws, size_t ws_size,
                              hipStream_t stream) {
    const float* node_attr  = (const float*)d_in[0];
    const int*   edge_index = (const int*)d_in[1];
    const float* edge_attr  = (const float*)d_in[2];
    const float* edge_sh    = (const float*)d_in[3];
    const float* fc_w1      = (const float*)d_in[4];
    const float* fc_b1      = (const float*)d_in[5];
    const float* fc_w2      = (const float*)d_in[6];
    const float* fc_b2      = (const float*)d_in[7];
    float* out = (float*)d_out;

    char* ws = (char*)d_ws;
    float* acc_g = (float*)ws;                                      // 8192*136*4 = 4456448
    float* cnt_g = (float*)(ws + 4456448);                          // 32768
    unsigned short* w2t = (unsigned short*)(ws + 4489216);          // 434176
    unsigned short* w1t = (unsigned short*)(ws + 4489216 + 434176); // 8192
    float* b2s = (float*)(ws + 4489216 + 434176 + 8192);            // 13568

    hipMemsetAsync(ws, 0, 4489216, stream);  // zero acc + cnt
    transpose_kernel<<<54, 256, 0, stream>>>(fc_w2, fc_w1, fc_b2, w2t, w1t, b2s);
    tpconv_main<<<1024, 256, 0, stream>>>(node_attr, edge_index, edge_attr, edge_sh,
                                          w1t, fc_b1, w2t, b2s, acc_g, cnt_g);
    finalize_kernel<<<(N_NODES * FEAT + 255) / 256, 256, 0, stream>>>(acc_g, cnt_g, node_attr, out);
}

// Round 2
// 164.811 us; speedup vs baseline: 1.3788x; 1.3788x over previous
//
#include <hip/hip_runtime.h>

#define N_NODES 8192
#define N_EDGES 65536
#define FEAT    136
#define WNUM    3392

typedef __attribute__((ext_vector_type(4))) short s16x4;
typedef __attribute__((ext_vector_type(8))) short s16x8;
typedef __attribute__((ext_vector_type(4))) float f32x4;
typedef __attribute__((ext_vector_type(2))) float f32x2;

__device__ __forceinline__ float b2f(unsigned short h) {
    union { unsigned int u; float f; } v; v.u = ((unsigned int)h) << 16; return v.f;
}
__device__ __forceinline__ unsigned short f2b(float f) {
    union { float f; unsigned int u; } v; v.f = f;
    unsigned int u = v.u;
    unsigned int r = (u + 0x7FFFu + ((u >> 16) & 1u)) >> 16;
    return (unsigned short)r;
}

// total scale for W2 column `col` = 1/sqrt(fan_in) * per-i sub-factor (inv_s3/inv_s2)
__device__ __forceinline__ float wscale(int col) {
    const float inv_s3 = 0.57735026918962576f;
    const float inv_s2 = 0.70710678118654752f;
    if (col < 1536) { int i = col >> 5;          return 0.14433756729740643f * (i < 32 ? 1.f : inv_s3); }
    if (col < 2560) { int i = (col - 1536) >> 4; return 0.125f               * (i >= 48 ? inv_s2 : 1.f); }
    if (col < 3200) { int i = (col - 2560) >> 4; return 0.15811388300841897f * (i < 16 ? inv_s2 : 1.f); }
    {               int i = (col - 3200) >> 3;   return 0.20412414523193150f * (i < 16 ? inv_s3 : 1.f); }
}

// ---- prep: W2 -> w2t in MFMA-fragment order; W1 -> w1t; b2 -> b2s; blocks >=54 zero acc/cnt ----
// w2t layout (shorts): [chunk c (64 cols)][t 0..3][half 0..1][lane 0..63][j 0..7]
//   element = W2scaled[k = half*32 + (lane>>4)*8 + j][col = c*64 + t*16 + (lane&15)]
__global__ void transpose_kernel(const float* __restrict__ w2,
                                 const float* __restrict__ w1,
                                 const float* __restrict__ bias2,
                                 unsigned short* __restrict__ w2t,
                                 unsigned short* __restrict__ w1t,
                                 float* __restrict__ b2s,
                                 float* __restrict__ zero_base) {
    __shared__ float tl[64 * 65];
    const int b = blockIdx.x, tid = threadIdx.x;
    if (b >= 54) {
        // zero acc_g + cnt_g: 4489216 bytes = 280576 float4, 1096 blocks x 256 threads
        int idx = (b - 54) * 256 + tid;
        float4 z = {0.f, 0.f, 0.f, 0.f};
        if (idx < 280576) ((float4*)zero_base)[idx] = z;
        return;
    }
    if (b < 53) {
        const int c0 = b * 64;
        for (int idx = tid; idx < 4096; idx += 256) {
            int k = idx >> 6, c = idx & 63;
            tl[c * 65 + k] = w2[k * WNUM + c0 + c];          // coalesced read over c
        }
        __syncthreads();
        for (int idx = tid; idx < 4096; idx += 256) {
            int fl   = idx >> 10;            // t
            int rem  = idx & 1023;
            int half = rem >> 9;
            int ln   = (rem >> 3) & 63;
            int j    = idx & 7;
            int q = ln >> 4, nn = ln & 15;
            int cl  = fl * 16 + nn;
            int k   = half * 32 + q * 8 + j;
            int col = c0 + cl;
            w2t[(size_t)b * 4096 + idx] = f2b(tl[cl * 65 + k] * wscale(col));
        }
        if (tid < 64) {
            int col = c0 + tid;
            b2s[col] = bias2[col] * wscale(col);
        }
    } else {
        for (int idx = tid; idx < 4096; idx += 256) {
            int k = idx >> 6, j = idx & 63;
            tl[j * 65 + k] = w1[k * 64 + j];
        }
        __syncthreads();
        for (int idx = tid; idx < 4096; idx += 256) {
            int j = idx >> 6, k = idx & 63;
            w1t[j * 64 + k] = f2b(tl[j * 65 + k]);
        }
    }
}

// async 16B/lane global -> LDS copy; LDS dest is wave-uniform base + lane*16
__device__ __forceinline__ void gload_lds16(const unsigned short* g, unsigned short* l) {
    __builtin_amdgcn_global_load_lds(
        (const __attribute__((address_space(1))) unsigned int*)g,
        (__attribute__((address_space(3))) unsigned int*)l, 16, 0, 0);
}

// ---------------- fused main kernel: 64 edges per block ----------------
__global__ __launch_bounds__(256, 4)
void tpconv_main(const float* __restrict__ node_attr,
                 const int* __restrict__ edge_index,
                 const float* __restrict__ edge_attr,
                 const float* __restrict__ edge_sh,
                 const unsigned short* __restrict__ w1t,
                 const float* __restrict__ b1,
                 const unsigned short* __restrict__ w2t,
                 const float* __restrict__ b2s,
                 float* __restrict__ acc_g,
                 float* __restrict__ cnt_g) {
    // LDS layout (37632 B -> 4 blocks/CU):
    //  [0, 18944)      x gather, bf16, 64 rows x stride 148          (live through K-loop)
    //  [18944, 35328)  W2 chunk double-buffer, 2 x 8192 B, LINEAR fragment order
    //     overlays (dead before staging starts):
    //     [18944, 28160)  h tile, bf16, 64 x 72
    //     [28160, 29184)  sh, f32, 64 x 4
    //     [29184, 29440)  dst (int 64)
    //  [37120, 37376)  src (int 64)  -- survives epilogue stage reuse
    //  epilogue: [0, 37120) reused as f32 Y staging, 64 rows x stride 145
    __shared__ __align__(16) char smem[37632];
    unsigned short* x_lds = (unsigned short*)smem;
    unsigned short* wbuf  = (unsigned short*)(smem + 18944);
    unsigned short* h_lds = (unsigned short*)(smem + 18944);
    float* sh_lds = (float*)(smem + 28160);
    int* dst_lds  = (int*)(smem + 29184);
    int* src_lds  = (int*)(smem + 37120);

    const int tid  = threadIdx.x;
    const int lane = tid & 63;
    const int wv   = tid >> 6;       // wave 0..3 -> 16-edge stripe
    const int n    = lane & 15;
    const int quad = lane >> 4;
    const int eb   = blockIdx.x * 64;

    // ---- phase A: indices, sh, counts + h = relu(ea @ W1 + b1) -> h_lds ----
    if (tid < 64) {
        int s = edge_index[eb + tid];
        int d = edge_index[N_EDGES + eb + tid];
        src_lds[tid] = s;
        dst_lds[tid] = d;
        atomicAdd(&cnt_g[s], 1.0f);
        const float4 shv = *(const float4*)&edge_sh[(size_t)(eb + tid) * 4];
        sh_lds[tid * 4 + 0] = shv.x;
        sh_lds[tid * 4 + 1] = shv.y;
        sh_lds[tid * 4 + 2] = shv.z;
        sh_lds[tid * 4 + 3] = shv.w;
    }
    {
        const float* ea = edge_attr + (size_t)(eb + wv * 16 + n) * 64 + quad * 8;
        s16x8 a0, a1;
#pragma unroll
        for (int j = 0; j < 8; ++j) {
            a0[j] = (short)f2b(ea[j]);        // A[m=n][k=quad*8+j]
            a1[j] = (short)f2b(ea[32 + j]);
        }
        for (int ct = 0; ct < 4; ++ct) {
            int col = ct * 16 + n;
            const unsigned short* wp = w1t + col * 64;
            s16x8 bu0 = *(const s16x8*)&wp[quad * 8];
            s16x8 bu1 = *(const s16x8*)&wp[32 + quad * 8];
            f32x4 acc = {0.f, 0.f, 0.f, 0.f};
            acc = __builtin_amdgcn_mfma_f32_16x16x32_bf16(a0, bu0, acc, 0, 0, 0);
            acc = __builtin_amdgcn_mfma_f32_16x16x32_bf16(a1, bu1, acc, 0, 0, 0);
            float bias = b1[col];
            for (int r = 0; r < 4; ++r) {
                float hv = acc[r] + bias;
                hv = hv > 0.f ? hv : 0.f;
                h_lds[(wv * 16 + quad * 4 + r) * 72 + col] = f2b(hv);
            }
        }
    }
    __syncthreads();   // h, dst, sh visible

    // ---- phase B: x gather (node_attr[dst] -> bf16) + pull h/sh into regs ----
    for (int idx = tid; idx < 64 * 34; idx += 256) {
        int e = idx / 34, seg = idx - e * 34;
        const float4 v = *(const float4*)(node_attr + (size_t)dst_lds[e] * FEAT + seg * 4);
        s16x4 pk;
        pk[0] = (short)f2b(v.x); pk[1] = (short)f2b(v.y);
        pk[2] = (short)f2b(v.z); pk[3] = (short)f2b(v.w);
        *(s16x4*)&x_lds[e * 148 + seg * 4] = pk;
    }
    const int eLoc = wv * 16 + n;
    const float sh0 = sh_lds[eLoc * 4 + 0];
    const float s1x = sh_lds[eLoc * 4 + 1];
    const float s1y = sh_lds[eLoc * 4 + 2];
    const float s1z = sh_lds[eLoc * 4 + 3];
    const unsigned short* hp = &h_lds[eLoc * 72];
    s16x8 h0 = *(const s16x8*)&hp[quad * 8];          // B[k=quad*8+j][n=edge]
    s16x8 h1 = *(const s16x8*)&hp[32 + quad * 8];
    const unsigned short* xr = &x_lds[eLoc * 148];

    __syncthreads();   // x visible; h/sh/dst now dead -> wbuf may overwrite

    // prologue: stage chunk 0 (drained by first in-loop barrier)
    {
        const unsigned short* g = w2t + (wv << 10) + (lane << 3);
        unsigned short* l = wbuf + (wv << 10);
        gload_lds16(g, l);
        gload_lds16(g + 512, l + 512);
    }

    f32x2 Y0e2[2][2] = {};   // [row-pair][kk]
    f32x2 Y1o2[2][3] = {};   // [row-pair][comp]
    f32x2 Y1e2[2][3] = {};
    f32x2 Y0o2[2]    = {};

    // Per-chunk top: barrier (drains stage of chunk c), issue stage c+1, load bias, set chunk base.
#define CHUNK_TOP(c)                                                          \
    __syncthreads();                                                          \
    if ((c) < 52) {                                                           \
        const unsigned short* g = w2t + (((size_t)(c) + 1) << 12) + (wv << 10) + (lane << 3); \
        unsigned short* l = wbuf + ((((c) + 1) & 1) << 12) + (wv << 10);      \
        gload_lds16(g, l);                                                    \
        gload_lds16(g + 512, l + 512);                                        \
    }                                                                         \
    f32x4 bvv[4];                                                             \
    _Pragma("unroll")                                                         \
    for (int t = 0; t < 4; ++t)                                               \
        bvv[t] = *(const f32x4*)(b2s + (c) * 64 + 16 * t + quad * 4);         \
    const unsigned short* cb = wbuf + (((c) & 1) << 12);

#define MFMA_T(t)                                                             \
    s16x8 aT0 = *(const s16x8*)&cb[(t) * 1024 + (lane << 3)];                 \
    s16x8 aT1 = *(const s16x8*)&cb[(t) * 1024 + 512 + (lane << 3)];           \
    f32x4 acc = bvv[t];                                                       \
    acc = __builtin_amdgcn_mfma_f32_16x16x32_bf16(aT0, h0, acc, 0, 0, 0);     \
    acc = __builtin_amdgcn_mfma_f32_16x16x32_bf16(aT1, h1, acc, 0, 0, 0);     \
    f32x2 a01 = {acc[0], acc[1]}; f32x2 a23 = {acc[2], acc[3]};

#define ACC3(Y)                                                               \
    Y[0][0] += a01 * o0; Y[1][0] += a23 * o0;                                 \
    Y[0][1] += a01 * o1; Y[1][1] += a23 * o1;                                 \
    Y[0][2] += a01 * o2; Y[1][2] += a23 * o2;

    // ---- 0e, i < 32: x0e[i]*sh0 ----
    for (int c = 0; c < 16; ++c) {
        CHUNK_TOP(c)
        float ov = 0.f;
#pragma unroll
        for (int t = 0; t < 4; ++t) {
            MFMA_T(t)
            if ((t & 1) == 0) ov = b2f(xr[2 * c + (t >> 1)]) * sh0;
            const int kk = t & 1;
            Y0e2[0][kk] += a01 * ov;
            Y0e2[1][kk] += a23 * ov;
        }
    }
    // ---- 0e, 32 <= i < 48: dot(x1o[i-32], sh1) ----
    for (int c = 16; c < 24; ++c) {
        CHUNK_TOP(c)
        float ov = 0.f;
#pragma unroll
        for (int t = 0; t < 4; ++t) {
            MFMA_T(t)
            if ((t & 1) == 0) {
                int ib = 32 + 3 * (2 * c + (t >> 1) - 32);
                ov = b2f(xr[ib]) * s1x + b2f(xr[ib + 1]) * s1y + b2f(xr[ib + 2]) * s1z;
            }
            const int kk = t & 1;
            Y0e2[0][kk] += a01 * ov;
            Y0e2[1][kk] += a23 * ov;
        }
    }
    // ---- 1o, i < 32: x0e[i]*sh1 ----
    for (int c = 24; c < 32; ++c) {
        CHUNK_TOP(c)
#pragma unroll
        for (int t = 0; t < 4; ++t) {
            MFMA_T(t)
            float xv = b2f(xr[4 * (c - 24) + t]);
            float o0 = xv * s1x, o1 = xv * s1y, o2 = xv * s1z;
            ACC3(Y1o2)
        }
    }
    // ---- 1o, 32 <= i < 48: x1o[i-32]*sh0 ----
    for (int c = 32; c < 36; ++c) {
        CHUNK_TOP(c)
#pragma unroll
        for (int t = 0; t < 4; ++t) {
            MFMA_T(t)
            int ib = 32 + 3 * (4 * (c - 24) + t - 32);
            float o0 = b2f(xr[ib]) * sh0, o1 = b2f(xr[ib + 1]) * sh0, o2 = b2f(xr[ib + 2]) * sh0;
            ACC3(Y1o2)
        }
    }
    // ---- 1o, i >= 48: cross(x1e[i-48], sh1) ----
    for (int c = 36; c < 40; ++c) {
        CHUNK_TOP(c)
#pragma unroll
        for (int t = 0; t < 4; ++t) {
            MFMA_T(t)
            int ib = 80 + 3 * (4 * (c - 24) + t - 48);
            float av0 = b2f(xr[ib]), av1 = b2f(xr[ib + 1]), av2 = b2f(xr[ib + 2]);
            float o0 = av1 * s1z - av2 * s1y;
            float o1 = av2 * s1x - av0 * s1z;
            float o2 = av0 * s1y - av1 * s1x;
            ACC3(Y1o2)
        }
    }
    // ---- 1e, i < 16: cross(x1o[i], sh1) ----
    for (int c = 40; c < 44; ++c) {
        CHUNK_TOP(c)
#pragma unroll
        for (int t = 0; t < 4; ++t) {
            MFMA_T(t)
            int ib = 32 + 3 * (4 * (c - 40) + t);
            float av0 = b2f(xr[ib]), av1 = b2f(xr[ib + 1]), av2 = b2f(xr[ib + 2]);
            float o0 = av1 * s1z - av2 * s1y;
            float o1 = av2 * s1x - av0 * s1z;
            float o2 = av0 * s1y - av1 * s1x;
            ACC3(Y1e2)
        }
    }
    // ---- 1e, 16 <= i < 32: x1e[i-16]*sh0 ----
    for (int c = 44; c < 48; ++c) {
        CHUNK_TOP(c)
#pragma unroll
        for (int t = 0; t < 4; ++t) {
            MFMA_T(t)
            int ib = 80 + 3 * (4 * (c - 40) + t - 16);
            float o0 = b2f(xr[ib]) * sh0, o1 = b2f(xr[ib + 1]) * sh0, o2 = b2f(xr[ib + 2]) * sh0;
            ACC3(Y1e2)
        }
    }
    // ---- 1e, i >= 32: x0o[i-32]*sh1 ----
    for (int c = 48; c < 50; ++c) {
        CHUNK_TOP(c)
#pragma unroll
        for (int t = 0; t < 4; ++t) {
            MFMA_T(t)
            float xv = b2f(xr[128 + (4 * (c - 40) + t - 32)]);
            float o0 = xv * s1x, o1 = xv * s1y, o2 = xv * s1z;
            ACC3(Y1e2)
        }
    }
    // ---- 0o, i < 16: dot(x1e[i], sh1) ----
    for (int c = 50; c < 52; ++c) {
        CHUNK_TOP(c)
#pragma unroll
        for (int t = 0; t < 4; ++t) {
            MFMA_T(t)
            int ib = 80 + 3 * (8 * (c - 50) + 2 * t + (quad >> 1));
            float ov = b2f(xr[ib]) * s1x + b2f(xr[ib + 1]) * s1y + b2f(xr[ib + 2]) * s1z;
            Y0o2[0] += a01 * ov;
            Y0o2[1] += a23 * ov;
        }
    }
    // ---- 0o, i >= 16: x0o[i-16]*sh0 ----
    {
        CHUNK_TOP(52)
#pragma unroll
        for (int t = 0; t < 4; ++t) {
            MFMA_T(t)
            float ov = b2f(xr[128 + 2 * t + (quad >> 1)]) * sh0;
            Y0o2[0] += a01 * ov;
            Y0o2[1] += a23 * ov;
        }
    }
#undef ACC3
#undef MFMA_T
#undef CHUNK_TOP

    // ---- stage Y rows in LDS (reuse x+wbuf region, stride 145), then coalesced atomics ----
    __syncthreads();                          // everyone done reading x / wbuf
    float* stage = (float*)smem;              // 64 rows x 145 f32
    {
        float* srow = stage + eLoc * 145;
#pragma unroll
        for (int r = 0; r < 4; ++r) {
            const int p = r >> 1, s = r & 1;
            int qr = quad * 4 + r;
            srow[qr]              = Y0e2[p][0][s];
            srow[16 + qr]         = Y0e2[p][1][s];
            srow[32 + qr * 3 + 0] = Y1o2[p][0][s];
            srow[32 + qr * 3 + 1] = Y1o2[p][1][s];
            srow[32 + qr * 3 + 2] = Y1o2[p][2][s];
            srow[80 + qr * 3 + 0] = Y1e2[p][0][s];
            srow[80 + qr * 3 + 1] = Y1e2[p][1][s];
            srow[80 + qr * 3 + 2] = Y1e2[p][2][s];
            srow[128 + (quad & 1) * 4 + r + (quad >> 1) * 8] = Y0o2[p][s];
        }
    }
    __syncthreads();
    // wave wv scatters its own 16 edges, lanes cover consecutive features (coalesced)
    for (int j = 0; j < 16; ++j) {
        int e = wv * 16 + j;
        float* dp = acc_g + (size_t)src_lds[e] * FEAT;
        const float* sr = stage + e * 145;
        atomicAdd(dp + lane,      sr[lane]);
        atomicAdd(dp + 64 + lane, sr[64 + lane]);
        if (lane < 8)
            atomicAdd(dp + 128 + lane, sr[128 + lane] + sr[136 + lane]);
    }
}

// ---------------- finalize: mean + residual (fp32 out) ----------------
__global__ void finalize_kernel(const float* __restrict__ acc_g,
                                const float* __restrict__ cnt_g,
                                const float* __restrict__ node_attr,
                                float* __restrict__ out) {
    int idx = blockIdx.x * 256 + threadIdx.x;
    if (idx >= N_NODES * FEAT) return;
    int nn = idx / FEAT;
    float c = cnt_g[nn];
    out[idx] = acc_g[idx] / fmaxf(c, 1.0f) + node_attr[idx];
}

extern "C" void kernel_launch(void* const* d_in, const int* in_sizes, int n_in,
                              void* d_out, int out_size, void* d_ws, size_t ws_size,
                              hipStream_t stream) {
    const float* node_attr  = (const float*)d_in[0];
    const int*   edge_index = (const int*)d_in[1];
    const float* edge_attr  = (const float*)d_in[2];
    const float* edge_sh    = (const float*)d_in[3];
    const float* fc_w1      = (const float*)d_in[4];
    const float* fc_b1      = (const float*)d_in[5];
    const float* fc_w2      = (const float*)d_in[6];
    const float* fc_b2      = (const float*)d_in[7];
    float* out = (float*)d_out;

    char* ws = (char*)d_ws;
    float* acc_g = (float*)ws;                                      // 8192*136*4 = 4456448
    float* cnt_g = (float*)(ws + 4456448);                          // 32768
    unsigned short* w2t = (unsigned short*)(ws + 4489216);          // 434176
    unsigned short* w1t = (unsigned short*)(ws + 4489216 + 434176); // 8192
    float* b2s = (float*)(ws + 4489216 + 434176 + 8192);            // 13568

    // blocks 0..52: W2 chunks; 53: W1; 54..1149: zero acc_g+cnt_g (replaces hipMemsetAsync)
    transpose_kernel<<<1150, 256, 0, stream>>>(fc_w2, fc_w1, fc_b2, w2t, w1t, b2s, acc_g);
    tpconv_main<<<1024, 256, 0, stream>>>(node_attr, edge_index, edge_attr, edge_sh,
                                          w1t, fc_b1, w2t, b2s, acc_g, cnt_g);
    finalize_kernel<<<(N_NODES * FEAT + 255) / 256, 256, 0, stream>>>(acc_g, cnt_g, node_attr, out);
}